// Round 9
// baseline (1940.593 us; speedup 1.0000x reference)
//
#include <hip/hip_runtime.h>
#include <hip/hip_bf16.h>

#define HID   1024
#define G3    3072
#define EMB   300
#define EMBP  320      // K padded to multiple of 32
#define VOCAB 3863
#define POSE  514
#define BATCH 128
#define TIN   64
#define TOUT  90
#define BH    (BATCH * HID)
#define NBLK  256

typedef __bf16 bf16x8 __attribute__((ext_vector_type(8)));
typedef float  f32x4  __attribute__((ext_vector_type(4)));
typedef __hip_bfloat16 bhalf;
typedef unsigned long long u64;

#define MFMA(a,b,c) __builtin_amdgcn_mfma_f32_16x16x32_bf16((a),(b),(c),0,0,0)

__device__ __forceinline__ float sigm(float x) { return 1.f / (1.f + __expf(-x)); }
__device__ __forceinline__ float tanh_f(float x) { return 1.f - 2.f / (__expf(2.f * x) + 1.f); }

// ---- coherent h-load (L1/L2-bypass, batchable): proven round 8 ----
#define COH_LD(dst, base, imm)                                            \
  asm volatile("global_load_dwordx4 %0, %1, off offset:%2 sc0 sc1"        \
               : "=v"(dst) : "v"(base), "i"(imm))
// ---- plain asm loads for tok/gi: kept OUT of compiler's vm accounting so
// our counted vmcnt waits stay exact (a C-level load would make the compiler
// emit a conservative vmcnt(0) at its use, draining the whole pipeline).
#define TOK_LD(dst, addr)                                                 \
  asm volatile("global_load_dword %0, %1, off" : "=v"(dst) : "v"(addr))
#define GI_LD(dst, addr, imm)                                             \
  asm volatile("global_load_ushort %0, %1, off offset:%2"                 \
               : "=v"(dst) : "v"(addr), "i"(imm))

__device__ __forceinline__ void coh_st_h(bhalf* p, float v) {
  union { bhalf b; unsigned short s; } u;
  u.b = __float2bfloat16(v);
  __hip_atomic_store((unsigned short*)p, u.s, __ATOMIC_RELAXED, __HIP_MEMORY_SCOPE_AGENT);
}
__device__ __forceinline__ void coh_st_f(float* p, float v) {
  __hip_atomic_store(p, v, __ATOMIC_RELAXED, __HIP_MEMORY_SCOPE_AGENT);
}
__device__ __forceinline__ float coh_ld_f(const float* p) {
  return __hip_atomic_load((const float*)p, __ATOMIC_RELAXED, __HIP_MEMORY_SCOPE_AGENT);
}

// ---- grid barrier, no cache-invalidating fence (h goes via coherent ops) ----
__device__ __forceinline__ void gbar(unsigned* bar, unsigned tgt) {
  __syncthreads();
  if (threadIdx.x == 0) {
    __hip_atomic_fetch_add(bar, 1u, __ATOMIC_RELEASE, __HIP_MEMORY_SCOPE_AGENT);
    while (__hip_atomic_load(bar, __ATOMIC_RELAXED, __HIP_MEMORY_SCOPE_AGENT) < tgt)
      __builtin_amdgcn_s_sleep(1);
  }
  __syncthreads();
  asm volatile("" ::: "memory");
}

__global__ void k_zerobar(unsigned* p) {
  int i = blockIdx.x * 256 + threadIdx.x;
  if (i < 1024)
    __hip_atomic_store(p + i, 0u, __ATOMIC_RELAXED, __HIP_MEMORY_SCOPE_AGENT);
}

// ---------- fp32 -> bf16 conversion with zero padding ----------
__global__ __launch_bounds__(256) void k_convert(const float* __restrict__ src,
        bhalf* __restrict__ dst, int rows_in, int cols_in, int cols_out, int total) {
  int i = blockIdx.x * 256 + threadIdx.x;
  if (i >= total) return;
  int r = i / cols_out, c = i - r * cols_out;
  float v = (r < rows_in && c < cols_in) ? src[(size_t)r * cols_in + c] : 0.f;
  dst[i] = __float2bfloat16(v);
}

// ---------- pack Whh [3H][H] -> [(j>>4)*48 + g*16 + (j&15)][k] bf16 ----------
__global__ __launch_bounds__(256) void k_pack(const float* __restrict__ whh,
                                              bhalf* __restrict__ dst) {
  int i = blockIdx.x * 256 + threadIdx.x;
  if (i >= G3 * HID) return;
  int k  = i & (HID - 1);
  int rp = i >> 10;
  int jg  = rp / 48;
  int rem = rp - jg * 48;
  int g = rem >> 4, jl = rem & 15;
  int j = (jg << 4) + jl;
  dst[i] = __float2bfloat16(whh[(size_t)((g << 10) + j) * HID + k]);
}

// ---------- MFMA GEMM-NT, XCD-chunked swizzle; OUTBF: bf16 C vs f32 C ----------
template<int OUTBF>
__global__ __launch_bounds__(256) void k_gemm(
    const bhalf* __restrict__ A, const bhalf* __restrict__ B,
    const float* __restrict__ bias, float* __restrict__ Cf, bhalf* __restrict__ Cb,
    int M, int K, int Nstore) {
  int gx = gridDim.x;
  int nwg = gx * gridDim.y;
  int orig = blockIdx.y * gx + blockIdx.x;
  int xcd = orig & 7, sl = orig >> 3;
  int qq = nwg >> 3, rr = nwg & 7;
  int nbid = (xcd < rr ? xcd * (qq + 1) : rr * (qq + 1) + (xcd - rr) * qq) + sl;
  int bx = nbid % gx, by = nbid / gx;

  int tid = threadIdx.x;
  int l = tid & 63, w = tid >> 6;
  int q = l >> 4, jl = l & 15;
  int n0 = bx * 32;
  int m0 = by * 128 + w * 32;
  int ar0 = m0 + jl;       if (ar0 >= M) ar0 = M - 1;
  int ar1 = m0 + 16 + jl;  if (ar1 >= M) ar1 = M - 1;
  const bhalf* pa0 = A + (size_t)ar0 * K + q * 8;
  const bhalf* pa1 = A + (size_t)ar1 * K + q * 8;
  const bhalf* pb0 = B + (size_t)(n0 + jl) * K + q * 8;
  const bhalf* pb1 = B + (size_t)(n0 + 16 + jl) * K + q * 8;
  f32x4 acc[2][2] = {};
#pragma unroll 4
  for (int kc = 0; kc < K; kc += 32) {
    bf16x8 a0 = *(const bf16x8*)(pa0 + kc);
    bf16x8 a1 = *(const bf16x8*)(pa1 + kc);
    bf16x8 b0 = *(const bf16x8*)(pb0 + kc);
    bf16x8 b1 = *(const bf16x8*)(pb1 + kc);
    acc[0][0] = MFMA(a0, b0, acc[0][0]);
    acc[0][1] = MFMA(a0, b1, acc[0][1]);
    acc[1][0] = MFMA(a1, b0, acc[1][0]);
    acc[1][1] = MFMA(a1, b1, acc[1][1]);
  }
#pragma unroll
  for (int sub = 0; sub < 2; ++sub)
#pragma unroll
    for (int ns = 0; ns < 2; ++ns)
#pragma unroll
      for (int reg = 0; reg < 4; ++reg) {
        int row = m0 + sub * 16 + q * 4 + reg;
        int col = n0 + ns * 16 + jl;
        if (row < M && col < Nstore) {
          float v = acc[sub][ns][reg] + bias[col];
          if (OUTBF) Cb[(size_t)row * Nstore + col] = __float2bfloat16(v);
          else       Cf[(size_t)row * Nstore + col] = v;
        }
      }
}

// ---------- persistent kernel ----------
// 256 blocks x 256 thr, 1 block/CU (132KB LDS). Block owns 16 j-cols; weights
// in XOR-swizzled LDS. 4 waves split K. Domain = 64 blocks. h exchanged via
// coherent ops. NEW (r9): gi/tok prefetched one step ahead (teacher forcing),
// h loads pipelined with counted vmcnt (all tok/gi/h loads are inline asm so
// the counts stay exact).
struct SeqArgs {
  const bhalf *packF, *packB, *packD;
  const bhalf *tabF, *tabB, *tabD;   // bf16 gi tables (bih folded)
  const float *bhhF, *bhhB, *bhhD;
  const int *in_text, *poses;
  bhalf *hb0F, *hb1F, *hb0B, *hb1B;  // enc bf16 h ping-pong, per dir
  float *hfinF, *hfinB;              // enc final fp32 h
  bhalf *h0bf;                       // dec_h0 bf16
  bhalf *hs;                         // [90][128][1024] decoder hidden chain
  unsigned *barF, *barE, *barD;      // full / encoder-domain / decoder-domain
};

__device__ __forceinline__ void load_w(char* wlds, const bhalf* wsrc, int tid) {
  for (int it = tid; it < 6144; it += 256) {
    int row = it >> 7, c8 = it & 127;
    int off = (row * 1024 + c8 * 8) * 2;
    *(bf16x8*)(wlds + (off ^ ((row & 7) << 4))) =
        *(const bf16x8*)(wsrc + row * 1024 + c8 * 8);
  }
}

__device__ __forceinline__ bf16x8 ldsB(const char* wlds, int row, int kcol) {
  int off = (row * 1024 + kcol) * 2;
  return *(const bf16x8*)(wlds + (off ^ ((row & 7) << 4)));
}

#define ENC_CHUNK(i) {                                                        \
  bf16x8 b0 = ldsB(wlds,      jl, kbase + (i) * 32 + q * 8);                  \
  bf16x8 b1 = ldsB(wlds, 16 + jl, kbase + (i) * 32 + q * 8);                  \
  bf16x8 b2 = ldsB(wlds, 32 + jl, kbase + (i) * 32 + q * 8);                  \
  acc[0][0] = MFMA(a0_[i], b0, acc[0][0]);                                    \
  acc[0][1] = MFMA(a0_[i], b1, acc[0][1]);                                    \
  acc[0][2] = MFMA(a0_[i], b2, acc[0][2]);                                    \
  acc[1][0] = MFMA(a1_[i], b0, acc[1][0]);                                    \
  acc[1][1] = MFMA(a1_[i], b1, acc[1][1]);                                    \
  acc[1][2] = MFMA(a1_[i], b2, acc[1][2]);                                    \
  acc[2][0] = MFMA(a2_[i], b0, acc[2][0]);                                    \
  acc[2][1] = MFMA(a2_[i], b1, acc[2][1]);                                    \
  acc[2][2] = MFMA(a2_[i], b2, acc[2][2]);                                    \
  acc[3][0] = MFMA(a3_[i], b0, acc[3][0]);                                    \
  acc[3][1] = MFMA(a3_[i], b1, acc[3][1]);                                    \
  acc[3][2] = MFMA(a3_[i], b2, acc[3][2]); }

#define DEC_CHUNK(i) {                                                        \
  bf16x8 b0 = ldsB(wlds,      jl, kbase + (i) * 32 + q * 8);                  \
  bf16x8 b1 = ldsB(wlds, 16 + jl, kbase + (i) * 32 + q * 8);                  \
  bf16x8 b2 = ldsB(wlds, 32 + jl, kbase + (i) * 32 + q * 8);                  \
  acc[0][0] = MFMA(a0_[i], b0, acc[0][0]);                                    \
  acc[0][1] = MFMA(a0_[i], b1, acc[0][1]);                                    \
  acc[0][2] = MFMA(a0_[i], b2, acc[0][2]);                                    \
  acc[1][0] = MFMA(a1_[i], b0, acc[1][0]);                                    \
  acc[1][1] = MFMA(a1_[i], b1, acc[1][1]);                                    \
  acc[1][2] = MFMA(a1_[i], b2, acc[1][2]); }

#define VMWAIT(N)                                                             \
  asm volatile("s_waitcnt vmcnt(" #N ")" ::: "memory");                       \
  __builtin_amdgcn_sched_barrier(0);

__global__ __launch_bounds__(256) __attribute__((amdgpu_waves_per_eu(1, 1)))
void k_seq(SeqArgs A) {
  __shared__ char  wlds[96 * 1024];
  __shared__ f32x4 part[3][4][3][64];   // writer-slot, m-tile, gate, lane
  int tid = threadIdx.x;
  int l = tid & 63, w = tid >> 6;       // wave 0..3 = K-quarter
  int q = l >> 4, jl = l & 15;
  int bid = blockIdx.x;
  int kbase = w * 256;

  // ===== encoder mapping: bid = dir*128 + mg*64 + jb =====
  int dir = bid >> 7;
  int mg  = (bid >> 6) & 1;
  int dom = bid >> 6;                   // 0..3
  int jb  = bid & 63;
  int m0  = mg * 64;
  int j   = jb * 16 + jl;
  const bhalf* Bp  = dir ? A.packB : A.packF;
  const bhalf* tab = dir ? A.tabB  : A.tabF;
  const float* bhh = dir ? A.bhhB  : A.bhhF;
  bhalf* hpp0 = dir ? A.hb0B : A.hb0F;
  bhalf* hpp1 = dir ? A.hb1B : A.hb1F;
  unsigned* myE = A.barE + (size_t)dom * 32;
  float bhr = bhh[j], bhz = bhh[HID + j], bhn = bhh[2 * HID + j];

  load_w(wlds, Bp + (size_t)jb * 48 * 1024, tid);

  // pre-loop gi prefetch for t=0 (plain loads, pre-pipeline so waits harmless)
  float curR[4], curZ[4], curN[4];
#pragma unroll
  for (int reg = 0; reg < 4; ++reg) {
    int m = m0 + w * 16 + q * 4 + reg;
    int tok = A.in_text[m * TIN + 0];
    const bhalf* gi = tab + (size_t)tok * G3;
    curR[reg] = __bfloat162float(gi[j]);
    curZ[reg] = __bfloat162float(gi[HID + j]);
    curN[reg] = __bfloat162float(gi[2 * HID + j]);
  }

  // zero owner slice of ping buffer 0
  float hreg[4] = {};
#pragma unroll
  for (int reg = 0; reg < 4; ++reg)
    coh_st_h(&hpp0[(size_t)(m0 + w * 16 + q * 4 + reg) * HID + j], 0.f);
  gbar(A.barF, NBLK);

  // ===== encoder: 64 steps =====
  unsigned et = 0;
  for (int t = 0; t < TIN; ++t) {
    const bhalf* hcur = (t & 1) ? hpp1 : hpp0;
    bhalf*       hnxt = (t & 1) ? hpp0 : hpp1;
    // (A) issue next-step token loads (asm; ops 1-4 in vm queue)
    int tn = (t + 1 < TIN) ? t + 1 : t;
    unsigned tkn[4];
#pragma unroll
    for (int reg = 0; reg < 4; ++reg) {
      const int* ta = A.in_text + (m0 + w * 16 + q * 4 + reg) * TIN + tn;
      TOK_LD(tkn[reg], ta);
    }
    // (B) issue h loads chunk-interleaved (ops 5-36)
    bf16x8 a0_[8], a1_[8], a2_[8], a3_[8];
    {
      const char* pm0 = (const char*)(hcur + (size_t)(m0 + jl) * HID + kbase + q * 8);
      const char* pm1 = pm0 + 32768;   // +16 rows
      const char* pm2 = pm0 + 65536;
      const char* pm3 = pm0 + 98304;
#pragma unroll
      for (int i = 0; i < 8; ++i) {
        COH_LD(a0_[i], pm0, i * 64);
        COH_LD(a1_[i], pm1, i * 64);
        COH_LD(a2_[i], pm2, i * 64);
        COH_LD(a3_[i], pm3, i * 64);
      }
    }
    f32x4 acc[4][3] = {};
    VMWAIT(24) ENC_CHUNK(0) ENC_CHUNK(1)      // chunks 0-1 (ops 5-12 retired)
    VMWAIT(16) ENC_CHUNK(2) ENC_CHUNK(3)      // chunks 2-3; toks retired too
    // (C) issue next-step gi loads (12 asm ushort loads)
    unsigned gR[4], gZ[4], gN[4];
#pragma unroll
    for (int reg = 0; reg < 4; ++reg) {
      const char* ga  = (const char*)(tab + (size_t)tkn[reg] * G3 + j);
      const char* ga2 = ga + 4096;
      GI_LD(gR[reg], ga, 0);
      GI_LD(gZ[reg], ga, 2048);
      GI_LD(gN[reg], ga2, 0);
    }
    VMWAIT(20) ENC_CHUNK(4) ENC_CHUNK(5)      // 8 h outstanding + 12 gi
    VMWAIT(12) ENC_CHUNK(6) ENC_CHUNK(7)      // 0 h outstanding + 12 gi
    // partials for non-owned m-tiles
#pragma unroll
    for (int mt = 0; mt < 4; ++mt) {
      if (mt != w) {
        int wi = w - (w > mt ? 1 : 0);
        part[wi][mt][0][l] = acc[mt][0];
        part[wi][mt][1][l] = acc[mt][1];
        part[wi][mt][2][l] = acc[mt][2];
      }
    }
    __syncthreads();
    f32x4 f0 = {}, f1 = {}, f2 = {};
#pragma unroll
    for (int mt = 0; mt < 4; ++mt)
      if (mt == w) { f0 = acc[mt][0]; f1 = acc[mt][1]; f2 = acc[mt][2]; }
#pragma unroll
    for (int s = 0; s < 3; ++s) {
      f0 += part[s][w][0][l]; f1 += part[s][w][1][l]; f2 += part[s][w][2][l];
    }
#pragma unroll
    for (int reg = 0; reg < 4; ++reg) {
      float r = sigm(curR[reg] + f0[reg] + bhr);
      float z = sigm(curZ[reg] + f1[reg] + bhz);
      float n = tanh_f(curN[reg] + r * (f2[reg] + bhn));
      float hv = (1.f - z) * n + z * hreg[reg];
      hreg[reg] = hv;
      coh_st_h(&hnxt[(size_t)(m0 + w * 16 + q * 4 + reg) * HID + j], hv);
    }
    et += 64;
    if (t < TIN - 1) gbar(myE, et);
    // gi prefetch landed during gates/stores/barrier; convert for next step
    VMWAIT(0)
#pragma unroll
    for (int reg = 0; reg < 4; ++reg) {
      curR[reg] = __uint_as_float(gR[reg] << 16);
      curZ[reg] = __uint_as_float(gZ[reg] << 16);
      curN[reg] = __uint_as_float(gN[reg] << 16);
    }
  }

  // ===== handoff: final fp32 h -> hfin; full barrier =====
  {
    float* hfin = dir ? A.hfinB : A.hfinF;
#pragma unroll
    for (int reg = 0; reg < 4; ++reg)
      coh_st_f(&hfin[(size_t)(m0 + w * 16 + q * 4 + reg) * HID + j], hreg[reg]);
  }
  gbar(A.barF, 2 * NBLK);

  // ===== decoder mapping: bid = dom2*64 + jb2; 32 rows, 2 m-tiles =====
  int dom2 = bid >> 6;
  int jb2  = bid & 63;
  int m20  = dom2 * 32;
  int j2   = jb2 * 16 + jl;
  unsigned* myD = A.barD + (size_t)dom2 * 32;
  float b2r = A.bhhD[j2], b2z = A.bhhD[HID + j2], b2n = A.bhhD[2 * HID + j2];

  load_w(wlds, A.packD + (size_t)jb2 * 48 * 1024, tid);

  // pre-loop gi prefetch for t=0 (pt=0)
#pragma unroll
  for (int reg = 0; reg < 4; ++reg) {
    int m = m20 + (w & 1) * 16 + q * 4 + reg;
    int tok = A.poses[m * TOUT + 0];
    const bhalf* gi = A.tabD + (size_t)tok * G3;
    curR[reg] = __bfloat162float(gi[j2]);
    curZ[reg] = __bfloat162float(gi[HID + j2]);
    curN[reg] = __bfloat162float(gi[2 * HID + j2]);
  }

  float hreg4[4];
  if (w < 2) {
#pragma unroll
    for (int reg = 0; reg < 4; ++reg) {
      int m = m20 + w * 16 + q * 4 + reg;
      float s = coh_ld_f(&A.hfinF[(size_t)m * HID + j2]) +
                coh_ld_f(&A.hfinB[(size_t)m * HID + j2]);
      hreg4[reg] = s;
      coh_st_h(&A.h0bf[(size_t)m * HID + j2], s);
    }
  }
  unsigned dt = 64;
  gbar(myD, dt);

  // ===== decoder: 90 steps =====
  for (int t = 0; t < TOUT; ++t) {
    const bhalf* Asrc = t ? (A.hs + (size_t)(t - 1) * BH) : A.h0bf;
    // (A) next-step token prefetch (pt for step t+1 is t); uniform on all waves
    int tnp = (t + 1 < TOUT) ? t : (t - 1);
    unsigned tkn[4];
#pragma unroll
    for (int reg = 0; reg < 4; ++reg) {
      const int* ta = A.poses + (m20 + (w & 1) * 16 + q * 4 + reg) * TOUT + tnp;
      TOK_LD(tkn[reg], ta);
    }
    // (B) h loads chunk-interleaved (ops 5-20)
    bf16x8 a0_[8], a1_[8];
    {
      const char* pm0 = (const char*)(Asrc + (size_t)(m20 + jl) * HID + kbase + q * 8);
      const char* pm1 = pm0 + 32768;
#pragma unroll
      for (int i = 0; i < 8; ++i) {
        COH_LD(a0_[i], pm0, i * 64);
        COH_LD(a1_[i], pm1, i * 64);
      }
    }
    f32x4 acc[2][3] = {};
    VMWAIT(12) DEC_CHUNK(0) DEC_CHUNK(1)
    VMWAIT(8)  DEC_CHUNK(2) DEC_CHUNK(3)
    unsigned gR[4], gZ[4], gN[4];
#pragma unroll
    for (int reg = 0; reg < 4; ++reg) {
      const char* ga  = (const char*)(A.tabD + (size_t)tkn[reg] * G3 + j2);
      const char* ga2 = ga + 4096;
      GI_LD(gR[reg], ga, 0);
      GI_LD(gZ[reg], ga, 2048);
      GI_LD(gN[reg], ga2, 0);
    }
    VMWAIT(16) DEC_CHUNK(4) DEC_CHUNK(5)
    VMWAIT(12) DEC_CHUNK(6) DEC_CHUNK(7)
#pragma unroll
    for (int mt = 0; mt < 2; ++mt) {
      if (mt != w) {
        int wi = w - (w > mt ? 1 : 0);
        part[wi][mt][0][l] = acc[mt][0];
        part[wi][mt][1][l] = acc[mt][1];
        part[wi][mt][2][l] = acc[mt][2];
      }
    }
    __syncthreads();
    if (w < 2) {
      f32x4 f0 = {}, f1 = {}, f2 = {};
#pragma unroll
      for (int mt = 0; mt < 2; ++mt)
        if (mt == w) { f0 = acc[mt][0]; f1 = acc[mt][1]; f2 = acc[mt][2]; }
#pragma unroll
      for (int s = 0; s < 3; ++s) {
        f0 += part[s][w][0][l]; f1 += part[s][w][1][l]; f2 += part[s][w][2][l];
      }
      bhalf* hout = A.hs + (size_t)t * BH;
#pragma unroll
      for (int reg = 0; reg < 4; ++reg) {
        float r = sigm(curR[reg] + f0[reg] + b2r);
        float z = sigm(curZ[reg] + f1[reg] + b2z);
        float n = tanh_f(curN[reg] + r * (f2[reg] + b2n));
        float hv = (1.f - z) * n + z * hreg4[reg];
        hreg4[reg] = hv;
        coh_st_h(&hout[(size_t)(m20 + w * 16 + q * 4 + reg) * HID + j2], hv);
      }
    }
    dt += 64;
    if (t < TOUT - 1) gbar(myD, dt);
    VMWAIT(0)
#pragma unroll
    for (int reg = 0; reg < 4; ++reg) {
      curR[reg] = __uint_as_float(gR[reg] << 16);
      curZ[reg] = __uint_as_float(gZ[reg] << 16);
      curN[reg] = __uint_as_float(gN[reg] << 16);
    }
  }
}

extern "C" void kernel_launch(void* const* d_in, const int* in_sizes, int n_in,
                              void* d_out, int out_size, void* d_ws, size_t ws_size,
                              hipStream_t stream) {
  const float* enc_emb   = (const float*)d_in[0];
  const float* enc_Wih_f = (const float*)d_in[1];
  const float* enc_Whh_f = (const float*)d_in[2];
  const float* enc_bih_f = (const float*)d_in[3];
  const float* enc_bhh_f = (const float*)d_in[4];
  const float* enc_Wih_b = (const float*)d_in[5];
  const float* enc_Whh_b = (const float*)d_in[6];
  const float* enc_bih_b = (const float*)d_in[7];
  const float* enc_bhh_b = (const float*)d_in[8];
  const float* dec_emb   = (const float*)d_in[9];
  const float* dec_Wih   = (const float*)d_in[10];
  const float* dec_Whh   = (const float*)d_in[11];
  const float* dec_bih   = (const float*)d_in[12];
  const float* dec_bhh   = (const float*)d_in[13];
  const float* fc_W      = (const float*)d_in[14];
  const float* fc_b      = (const float*)d_in[15];
  const int*   in_text   = (const int*)d_in[16];
  const int*   poses     = (const int*)d_in[18];
  float* out = (float*)d_out;

  char* p = (char*)d_ws;
  auto alloc = [&](size_t n) { char* r = p; p += (n + 255) & ~(size_t)255; return r; };
  bhalf* tabF  = (bhalf*)alloc((size_t)VOCAB * G3 * 2);
  bhalf* tabB  = (bhalf*)alloc((size_t)VOCAB * G3 * 2);
  bhalf* tabD  = (bhalf*)alloc((size_t)POSE * G3 * 2);
  bhalf* hb0F  = (bhalf*)alloc(BH * 2);
  bhalf* hb1F  = (bhalf*)alloc(BH * 2);
  bhalf* hb0B  = (bhalf*)alloc(BH * 2);
  bhalf* hb1B  = (bhalf*)alloc(BH * 2);
  float* hfinF = (float*)alloc(BH * 4);
  float* hfinB = (float*)alloc(BH * 4);
  bhalf* h0bf  = (bhalf*)alloc(BH * 2);
  bhalf* hs    = (bhalf*)alloc((size_t)TOUT * BH * 2);
  bhalf* embbf = (bhalf*)alloc((size_t)VOCAB * EMBP * 2);
  bhalf* wihF  = (bhalf*)alloc((size_t)G3 * EMBP * 2);
  bhalf* wihB  = (bhalf*)alloc((size_t)G3 * EMBP * 2);
  bhalf* dembbf= (bhalf*)alloc((size_t)POSE * HID * 2);
  bhalf* dwih  = (bhalf*)alloc((size_t)G3 * HID * 2);
  bhalf* fcw   = (bhalf*)alloc((size_t)544 * HID * 2);
  bhalf* packF = (bhalf*)alloc((size_t)G3 * HID * 2);
  bhalf* packB = (bhalf*)alloc((size_t)G3 * HID * 2);
  bhalf* packD = (bhalf*)alloc((size_t)G3 * HID * 2);
  unsigned* bars = (unsigned*)alloc(4096);
  unsigned* barF = bars;               // 1 counter (padded)
  unsigned* barE = bars + 32;          // 4 domain counters x 32 uints
  unsigned* barD = bars + 32 + 4 * 32; // 4 domain counters

  auto cgrid = [](int total) { return dim3((total + 255) / 256); };

  // one-off conversions / packing (+ barrier counters zero)
  k_zerobar<<<dim3(4), 256, 0, stream>>>(bars);
  k_convert<<<cgrid(VOCAB * EMBP), 256, 0, stream>>>(enc_emb, embbf, VOCAB, EMB, EMBP, VOCAB * EMBP);
  k_convert<<<cgrid(G3 * EMBP),   256, 0, stream>>>(enc_Wih_f, wihF, G3, EMB, EMBP, G3 * EMBP);
  k_convert<<<cgrid(G3 * EMBP),   256, 0, stream>>>(enc_Wih_b, wihB, G3, EMB, EMBP, G3 * EMBP);
  k_convert<<<cgrid(POSE * HID),  256, 0, stream>>>(dec_emb, dembbf, POSE, HID, HID, POSE * HID);
  k_convert<<<cgrid(G3 * HID),    256, 0, stream>>>(dec_Wih, dwih, G3, HID, HID, G3 * HID);
  k_convert<<<cgrid(544 * HID),   256, 0, stream>>>(fc_W, fcw, POSE, HID, HID, 544 * HID);
  k_pack<<<cgrid(G3 * HID), 256, 0, stream>>>(enc_Whh_f, packF);
  k_pack<<<cgrid(G3 * HID), 256, 0, stream>>>(enc_Whh_b, packB);
  k_pack<<<cgrid(G3 * HID), 256, 0, stream>>>(dec_Whh, packD);

  // gi tables (bf16, bih folded)
  k_gemm<1><<<dim3(96, 31), 256, 0, stream>>>(embbf, wihF, enc_bih_f, nullptr, tabF, VOCAB, EMBP, G3);
  k_gemm<1><<<dim3(96, 31), 256, 0, stream>>>(embbf, wihB, enc_bih_b, nullptr, tabB, VOCAB, EMBP, G3);
  k_gemm<1><<<dim3(96, 5),  256, 0, stream>>>(dembbf, dwih, dec_bih, nullptr, tabD, POSE, HID, G3);

  // persistent enc+dec
  SeqArgs sa;
  sa.packF = packF; sa.packB = packB; sa.packD = packD;
  sa.tabF = tabF; sa.tabB = tabB; sa.tabD = tabD;
  sa.bhhF = enc_bhh_f; sa.bhhB = enc_bhh_b; sa.bhhD = dec_bhh;
  sa.in_text = in_text; sa.poses = poses;
  sa.hb0F = hb0F; sa.hb1F = hb1F; sa.hb0B = hb0B; sa.hb1B = hb1B;
  sa.hfinF = hfinF; sa.hfinB = hfinB; sa.h0bf = h0bf; sa.hs = hs;
  sa.barF = barF; sa.barE = barE; sa.barD = barD;
  k_seq<<<dim3(NBLK), dim3(256), 0, stream>>>(sa);

  // output projection
  k_gemm<0><<<dim3(17, 90), 256, 0, stream>>>(hs, fcw, fc_b, out, nullptr, TOUT * BATCH, HID, POSE);
}